// Round 2
// baseline (198.362 us; speedup 1.0000x reference)
//
#include <hip/hip_runtime.h>
#include <hip/hip_cooperative_groups.h>
#include <cstddef>

namespace cg = cooperative_groups;

#define Hn 1024
#define Vn 32000
#define Sn 4096

__device__ __forceinline__ float wave_reduce_sum(float v) {
#pragma unroll
    for (int o = 32; o > 0; o >>= 1) v += __shfl_down(v, o, 64);
    return v;
}
__device__ __forceinline__ float wave_reduce_max(float v) {
#pragma unroll
    for (int o = 32; o > 0; o >>= 1) v = fmaxf(v, __shfl_down(v, o, 64));
    return v;
}

// ws layout (floats):
// [0,1024)      h            (c2 = [h, context] contiguous)
// [1024,2048)   context
// [2048,3072)   v = attn_w^T h
// [3072,7168)   scores
// [7168,72704)  partials (64 x 1024)

// ============ fused front chain: GRU -> attn_v -> scores -> softmax -> context ============
__global__ __launch_bounds__(256) void k_fused(const int* __restrict__ word,
                                               const float* __restrict__ emb,
                                               const float* __restrict__ h0,
                                               const float* __restrict__ w_ih,
                                               const float* __restrict__ w_hh,
                                               const float* __restrict__ b_ih,
                                               const float* __restrict__ b_hh,
                                               const float* __restrict__ attn_w,
                                               const float* __restrict__ enc,
                                               float* __restrict__ ws_h,
                                               float* __restrict__ ws_v,
                                               float* __restrict__ ws_scores,
                                               float* __restrict__ ws_part,
                                               float* __restrict__ ws_ctx,
                                               float* __restrict__ out_h,
                                               float* __restrict__ out_attn)
{
    cg::grid_group grid = cg::this_grid();
    const int t = threadIdx.x, bid = blockIdx.x;
    const int wv = t >> 6, lane = t & 63;
    __shared__ float smem[1024];

    // ---- Stage 1: GRU. wave handles output k = bid*4 + wv ----
    {
        const int k = bid * 4 + wv;
        const float* x = emb + (size_t)word[0] * Hn;
        float4 xv[4], hv[4];
#pragma unroll
        for (int i = 0; i < 4; ++i) {
            const int idx = i * 256 + lane * 4;
            xv[i] = *(const float4*)(x + idx);
            hv[i] = *(const float4*)(h0 + idx);
        }
        const float* rowp[6] = {
            w_ih + (size_t)k * Hn, w_ih + (size_t)(k + Hn) * Hn, w_ih + (size_t)(k + 2 * Hn) * Hn,
            w_hh + (size_t)k * Hn, w_hh + (size_t)(k + Hn) * Hn, w_hh + (size_t)(k + 2 * Hn) * Hn
        };
        float acc[6];
#pragma unroll
        for (int g = 0; g < 6; ++g) {
            float a = 0.f;
#pragma unroll
            for (int i = 0; i < 4; ++i) {
                const int idx = i * 256 + lane * 4;
                const float4 w4 = *(const float4*)(rowp[g] + idx);
                const float4 vv = (g < 3) ? xv[i] : hv[i];
                a += w4.x * vv.x + w4.y * vv.y + w4.z * vv.z + w4.w * vv.w;
            }
            acc[g] = wave_reduce_sum(a);
        }
        if (lane == 0) {
            const float g0 = acc[0] + b_ih[k], g1 = acc[1] + b_ih[k + Hn], g2 = acc[2] + b_ih[k + 2 * Hn];
            const float g3 = acc[3] + b_hh[k], g4 = acc[4] + b_hh[k + Hn], g5 = acc[5] + b_hh[k + 2 * Hn];
            const float r = 1.f / (1.f + expf(-(g0 + g3)));
            const float z = 1.f / (1.f + expf(-(g1 + g4)));
            const float n = tanhf(g2 + r * g5);
            const float hk = (1.f - z) * n + z * h0[k];
            ws_h[k]  = hk;
            out_h[k] = hk;
        }
    }
    grid.sync();

    // ---- Stage 2: v = attn_w^T h (blocks 0..63, 16-col strip each) ----
    if (bid < 64) {
        const int tj = t >> 4, tk = t & 15;
        const int k = bid * 16 + tk;
        float acc = 0.f;
        for (int j = tj; j < Hn; j += 16)
            acc += attn_w[(size_t)j * Hn + k] * ws_h[j];
        smem[tj * 17 + tk] = acc;
        __syncthreads();
        if (t < 16) {
            float s = 0.f;
#pragma unroll
            for (int j = 0; j < 16; ++j) s += smem[j * 17 + t];
            ws_v[bid * 16 + t] = s;
        }
    }
    grid.sync();

    // ---- Stage 3: scores[s] = enc[s].v  (16 scores per block) ----
    {
        ((float4*)smem)[t] = ((const float4*)ws_v)[t];
        __syncthreads();
#pragma unroll
        for (int q = 0; q < 4; ++q) {
            const int s = bid * 16 + wv * 4 + q;
            const float* row = enc + (size_t)s * Hn;
            float a = 0.f;
#pragma unroll
            for (int i = 0; i < 4; ++i) {
                const int idx = i * 256 + lane * 4;
                const float4 e = *(const float4*)(row + idx);
                a += e.x * smem[idx] + e.y * smem[idx + 1] + e.z * smem[idx + 2] + e.w * smem[idx + 3];
            }
            a = wave_reduce_sum(a);
            if (lane == 0) ws_scores[s] = a;
        }
    }
    grid.sync();

    // ---- Stage 4: per-block softmax stats over all 4096 scores ----
    float mx, inv;
    {
        float4 sc[4];
#pragma unroll
        for (int i = 0; i < 4; ++i) sc[i] = ((const float4*)ws_scores)[i * 256 + t];
        float m = -1e30f;
#pragma unroll
        for (int i = 0; i < 4; ++i)
            m = fmaxf(m, fmaxf(fmaxf(sc[i].x, sc[i].y), fmaxf(sc[i].z, sc[i].w)));
        m = wave_reduce_max(m);
        if (lane == 0) smem[wv] = m;
        __syncthreads();
        mx = fmaxf(fmaxf(smem[0], smem[1]), fmaxf(smem[2], smem[3]));
        float ps = 0.f;
#pragma unroll
        for (int i = 0; i < 4; ++i)
            ps += expf(sc[i].x - mx) + expf(sc[i].y - mx) + expf(sc[i].z - mx) + expf(sc[i].w - mx);
        ps = wave_reduce_sum(ps);
        __syncthreads();               // all waves done reading smem[0..3] (max)
        if (lane == 0) smem[wv] = ps;
        __syncthreads();
        inv = 1.f / (smem[0] + smem[1] + smem[2] + smem[3]);
    }

    // ---- Stage 5a: context partials. block (sc=bid>>2, jc=bid&3) ----
    {
        const int jc = bid & 3, sc = bid >> 2;
        const int j = jc * 256 + t;
        const int s0 = sc * 64;
        float acc = 0.f;
        for (int s = s0; s < s0 + 64; ++s) {
            const float a = expf(ws_scores[s] - mx) * inv;
            acc += a * enc[(size_t)s * Hn + j];
        }
        ws_part[(size_t)sc * Hn + j] = acc;
        if (jc == 0 && t < 64)
            out_attn[s0 + t] = expf(ws_scores[s0 + t] - mx) * inv;
    }
    grid.sync();

    // ---- Stage 5b: reduce partials -> context (blocks 0..3) ----
    if (bid < 4) {
        const int j = bid * 256 + t;
        float acc = 0.f;
#pragma unroll
        for (int sc2 = 0; sc2 < 64; ++sc2) acc += ws_part[(size_t)sc2 * Hn + j];
        ws_ctx[j] = acc;
    }
}

// ============ K6: output = out_w . [h, ctx] + out_b ============
__global__ __launch_bounds__(256) void k_out(const float* __restrict__ out_w,
                                             const float* __restrict__ out_b,
                                             const float* __restrict__ c2,
                                             float* __restrict__ out)
{
    __shared__ float c[2 * Hn];
    const int t = threadIdx.x;
    ((float4*)c)[t]       = ((const float4*)c2)[t];
    ((float4*)c)[t + 256] = ((const float4*)c2)[t + 256];
    __syncthreads();
    const int wv = t >> 6, lane = t & 63;
    const int row = blockIdx.x * 4 + wv;
    const float* w = out_w + (size_t)row * (2 * Hn);
    float acc = 0.f;
#pragma unroll
    for (int k = 0; k < 8; ++k) {
        const int idx = k * 256 + lane * 4;
        const float4 w4 = *(const float4*)(w + idx);
        acc += w4.x * c[idx] + w4.y * c[idx + 1] + w4.z * c[idx + 2] + w4.w * c[idx + 3];
    }
    acc = wave_reduce_sum(acc);
    if (lane == 0) out[row] = acc + out_b[row];
}

extern "C" void kernel_launch(void* const* d_in, const int* in_sizes, int n_in,
                              void* d_out, int out_size, void* d_ws, size_t ws_size,
                              hipStream_t stream) {
    const int*   word   = (const int*)d_in[0];
    const float* h_last = (const float*)d_in[1];
    const float* enc    = (const float*)d_in[2];
    const float* emb    = (const float*)d_in[3];
    const float* w_ih   = (const float*)d_in[4];
    const float* w_hh   = (const float*)d_in[5];
    const float* b_ih   = (const float*)d_in[6];
    const float* b_hh   = (const float*)d_in[7];
    const float* attn_w = (const float*)d_in[8];
    /* d_in[9] attn_b: unused — uniform shift, softmax-invariant */
    const float* out_w  = (const float*)d_in[10];
    const float* out_b  = (const float*)d_in[11];
    float* out = (float*)d_out;
    float* ws  = (float*)d_ws;

    float* ws_h      = ws;          // 1024
    float* ws_ctx    = ws + 1024;   // 1024 (c2 = [h, ctx] contiguous at ws)
    float* ws_v      = ws + 2048;   // 1024
    float* ws_scores = ws + 3072;   // 4096
    float* ws_part   = ws + 7168;   // 64*1024
    float* out_h     = out + Vn;
    float* out_attn  = out + Vn + Hn;

    void* args[] = {
        (void*)&word, (void*)&emb, (void*)&h_last, (void*)&w_ih, (void*)&w_hh,
        (void*)&b_ih, (void*)&b_hh, (void*)&attn_w, (void*)&enc,
        (void*)&ws_h, (void*)&ws_v, (void*)&ws_scores, (void*)&ws_part, (void*)&ws_ctx,
        (void*)&out_h, (void*)&out_attn
    };
    hipLaunchCooperativeKernel((void*)k_fused, dim3(256), dim3(256), args, 0, stream);
    k_out<<<Vn / 4, 256, 0, stream>>>(out_w, out_b, ws, out);
}

// Round 3
// 128.948 us; speedup vs baseline: 1.5383x; 1.5383x over previous
//
#include <hip/hip_runtime.h>
#include <cstddef>

#define Hn 1024
#define Vn 32000
#define Sn 4096

__device__ __forceinline__ float wave_reduce_sum(float v) {
#pragma unroll
    for (int o = 32; o > 0; o >>= 1) v += __shfl_down(v, o, 64);
    return v;
}
__device__ __forceinline__ float wave_reduce_max(float v) {
#pragma unroll
    for (int o = 32; o > 0; o >>= 1) v = fmaxf(v, __shfl_down(v, o, 64));
    return v;
}

// ws layout (floats):
// [0,1024)      h            (c2 = [h, context] contiguous)
// [1024,2048)   context
// [2048,3072)   v = attn_w^T h
// [3072,7168)   scores
// [7168,39936)  partials (32 x 1024)

// ---------------- K1: GRU cell -> h  (256 blocks, wave per output) ----------------
__global__ __launch_bounds__(256) void k_gru(const int* __restrict__ word,
                                             const float* __restrict__ emb,
                                             const float* __restrict__ h0,
                                             const float* __restrict__ w_ih,
                                             const float* __restrict__ w_hh,
                                             const float* __restrict__ b_ih,
                                             const float* __restrict__ b_hh,
                                             float* __restrict__ ws_h,
                                             float* __restrict__ out_h)
{
    const int t = threadIdx.x, bid = blockIdx.x;
    const int wv = t >> 6, lane = t & 63;
    const int k = bid * 4 + wv;
    const float* x = emb + (size_t)word[0] * Hn;

    float4 xv[4], hv[4];
#pragma unroll
    for (int i = 0; i < 4; ++i) {
        const int idx = i * 256 + lane * 4;
        xv[i] = *(const float4*)(x + idx);
        hv[i] = *(const float4*)(h0 + idx);
    }
    const float* rowp[6] = {
        w_ih + (size_t)k * Hn, w_ih + (size_t)(k + Hn) * Hn, w_ih + (size_t)(k + 2 * Hn) * Hn,
        w_hh + (size_t)k * Hn, w_hh + (size_t)(k + Hn) * Hn, w_hh + (size_t)(k + 2 * Hn) * Hn
    };
    float acc[6];
#pragma unroll
    for (int g = 0; g < 6; ++g) {
        float a = 0.f;
#pragma unroll
        for (int i = 0; i < 4; ++i) {
            const int idx = i * 256 + lane * 4;
            const float4 w4 = *(const float4*)(rowp[g] + idx);
            const float4 vv = (g < 3) ? xv[i] : hv[i];
            a += w4.x * vv.x + w4.y * vv.y + w4.z * vv.z + w4.w * vv.w;
        }
        acc[g] = wave_reduce_sum(a);
    }
    if (lane == 0) {
        const float g0 = acc[0] + b_ih[k], g1 = acc[1] + b_ih[k + Hn], g2 = acc[2] + b_ih[k + 2 * Hn];
        const float g3 = acc[3] + b_hh[k], g4 = acc[4] + b_hh[k + Hn], g5 = acc[5] + b_hh[k + 2 * Hn];
        const float r = 1.f / (1.f + expf(-(g0 + g3)));
        const float z = 1.f / (1.f + expf(-(g1 + g4)));
        const float n = tanhf(g2 + r * g5);
        const float hk = (1.f - z) * n + z * h0[k];
        ws_h[k]  = hk;
        out_h[k] = hk;
    }
}

// ---------------- K2: v = attn_w^T h  (32 blocks, k-strip of 32) ----------------
__global__ __launch_bounds__(256) void k_attnv(const float* __restrict__ attn_w,
                                               const float* __restrict__ ws_h,
                                               float* __restrict__ v)
{
    const int t = threadIdx.x;
    const int kk = t & 31;            // column within strip
    const int jg = t >> 5;            // 0..7 row-group
    const int k = blockIdx.x * 32 + kk;
    float acc = 0.f;
    for (int j = jg; j < Hn; j += 8)
        acc += attn_w[(size_t)j * Hn + k] * ws_h[j];
    __shared__ float p[8][33];
    p[jg][kk] = acc;
    __syncthreads();
    if (t < 32) {
        float s = 0.f;
#pragma unroll
        for (int j = 0; j < 8; ++j) s += p[j][t];
        v[blockIdx.x * 32 + t] = s;
    }
}

// ---------------- K3: scores[s] = enc[s] . v ----------------
__global__ __launch_bounds__(256) void k_scores(const float* __restrict__ enc,
                                                const float* __restrict__ ws_v,
                                                float* __restrict__ scores)
{
    __shared__ float v[Hn];
    const int t = threadIdx.x;
    ((float4*)v)[t] = ((const float4*)ws_v)[t];
    __syncthreads();
    const int wv = t >> 6, lane = t & 63;
    const int s = blockIdx.x * 4 + wv;
    const float* row = enc + (size_t)s * Hn;
    float acc = 0.f;
#pragma unroll
    for (int k = 0; k < 4; ++k) {
        const int idx = k * 256 + lane * 4;
        const float4 e = *(const float4*)(row + idx);
        acc += e.x * v[idx] + e.y * v[idx + 1] + e.z * v[idx + 2] + e.w * v[idx + 3];
    }
    acc = wave_reduce_sum(acc);
    if (lane == 0) scores[s] = acc;
}

// ---------------- K4: softmax(recomputed per block) + context partials ----------------
__global__ __launch_bounds__(256) void k_ctx(const float* __restrict__ enc,
                                             const float* __restrict__ scores,
                                             float* __restrict__ partial,
                                             float* __restrict__ out_attn)
{
    const int t = threadIdx.x, bid = blockIdx.x;
    const int wv = t >> 6, lane = t & 63;
    __shared__ float red[4];
    __shared__ float aw[128];

    // softmax stats over all 4096 scores (redundant per block; scores are L2-hot)
    float4 sc[4];
#pragma unroll
    for (int i = 0; i < 4; ++i) sc[i] = ((const float4*)scores)[i * 256 + t];
    float m = -1e30f;
#pragma unroll
    for (int i = 0; i < 4; ++i)
        m = fmaxf(m, fmaxf(fmaxf(sc[i].x, sc[i].y), fmaxf(sc[i].z, sc[i].w)));
    m = wave_reduce_max(m);
    if (lane == 0) red[wv] = m;
    __syncthreads();
    const float mx = fmaxf(fmaxf(red[0], red[1]), fmaxf(red[2], red[3]));
    float ps = 0.f;
#pragma unroll
    for (int i = 0; i < 4; ++i)
        ps += expf(sc[i].x - mx) + expf(sc[i].y - mx) + expf(sc[i].z - mx) + expf(sc[i].w - mx);
    ps = wave_reduce_sum(ps);
    __syncthreads();
    if (lane == 0) red[wv] = ps;
    __syncthreads();
    const float inv = 1.f / (red[0] + red[1] + red[2] + red[3]);

    // context partial: block (sc_chunk = bid>>2, jc = bid&3), s-chunk of 128
    const int jc = bid & 3, scc = bid >> 2;
    const int j = jc * 256 + t;
    const int s0 = scc * 128;
    if (t < 128) aw[t] = expf(scores[s0 + t] - mx) * inv;
    __syncthreads();
    float acc = 0.f;
#pragma unroll 4
    for (int s = 0; s < 128; ++s)
        acc += aw[s] * enc[(size_t)(s0 + s) * Hn + j];
    partial[(size_t)scc * Hn + j] = acc;
    if (jc == 0 && t < 128) out_attn[s0 + t] = aw[t];
}

// ---------------- K5: reduce partials -> context ----------------
__global__ __launch_bounds__(256) void k_ctx_red(const float* __restrict__ partial,
                                                 float* __restrict__ ctx)
{
    const int j = blockIdx.x * 256 + threadIdx.x;
    float acc = 0.f;
#pragma unroll
    for (int sc = 0; sc < 32; ++sc) acc += partial[(size_t)sc * Hn + j];
    ctx[j] = acc;
}

// ---------------- K6: output = out_w . [h, ctx] + out_b ----------------
__global__ __launch_bounds__(256) void k_out(const float* __restrict__ out_w,
                                             const float* __restrict__ out_b,
                                             const float* __restrict__ c2,
                                             float* __restrict__ out)
{
    __shared__ float c[2 * Hn];
    const int t = threadIdx.x;
    ((float4*)c)[t]       = ((const float4*)c2)[t];
    ((float4*)c)[t + 256] = ((const float4*)c2)[t + 256];
    __syncthreads();
    const int wv = t >> 6, lane = t & 63;
    const int row = blockIdx.x * 4 + wv;
    const float* w = out_w + (size_t)row * (2 * Hn);
    float acc = 0.f;
#pragma unroll
    for (int k = 0; k < 8; ++k) {
        const int idx = k * 256 + lane * 4;
        const float4 w4 = *(const float4*)(w + idx);
        acc += w4.x * c[idx] + w4.y * c[idx + 1] + w4.z * c[idx + 2] + w4.w * c[idx + 3];
    }
    acc = wave_reduce_sum(acc);
    if (lane == 0) out[row] = acc + out_b[row];
}

extern "C" void kernel_launch(void* const* d_in, const int* in_sizes, int n_in,
                              void* d_out, int out_size, void* d_ws, size_t ws_size,
                              hipStream_t stream) {
    const int*   word   = (const int*)d_in[0];
    const float* h_last = (const float*)d_in[1];
    const float* enc    = (const float*)d_in[2];
    const float* emb    = (const float*)d_in[3];
    const float* w_ih   = (const float*)d_in[4];
    const float* w_hh   = (const float*)d_in[5];
    const float* b_ih   = (const float*)d_in[6];
    const float* b_hh   = (const float*)d_in[7];
    const float* attn_w = (const float*)d_in[8];
    /* d_in[9] attn_b: unused — uniform shift, softmax-invariant */
    const float* out_w  = (const float*)d_in[10];
    const float* out_b  = (const float*)d_in[11];
    float* out = (float*)d_out;
    float* ws  = (float*)d_ws;

    float* ws_h      = ws;          // 1024
    float* ws_ctx    = ws + 1024;   // 1024 (c2 = [h, ctx] contiguous at ws)
    float* ws_v      = ws + 2048;   // 1024
    float* ws_scores = ws + 3072;   // 4096
    float* ws_part   = ws + 7168;   // 32*1024

    k_gru<<<Hn / 4, 256, 0, stream>>>(word, emb, h_last, w_ih, w_hh, b_ih, b_hh, ws_h, out + Vn);
    k_attnv<<<Hn / 32, 256, 0, stream>>>(attn_w, ws_h, ws_v);
    k_scores<<<Sn / 4, 256, 0, stream>>>(enc, ws_v, ws_scores);
    k_ctx<<<128, 256, 0, stream>>>(enc, ws_scores, ws_part, out + Vn + Hn);
    k_ctx_red<<<4, 256, 0, stream>>>(ws_part, ws_ctx);
    k_out<<<Vn / 4, 256, 0, stream>>>(out_w, out_b, ws, out);
}

// Round 4
// 86.191 us; speedup vs baseline: 2.3014x; 1.4961x over previous
//
#include <hip/hip_runtime.h>
#include <cstddef>

#define Hn 1024
#define Vn 32000
#define Sn 4096

__device__ __forceinline__ float wave_reduce_sum(float v) {
#pragma unroll
    for (int o = 32; o > 0; o >>= 1) v += __shfl_down(v, o, 64);
    return v;
}
__device__ __forceinline__ float wave_reduce_max(float v) {
#pragma unroll
    for (int o = 32; o > 0; o >>= 1) v = fmaxf(v, __shfl_down(v, o, 64));
    return v;
}

// ws layout (floats):
// [0,1024)      h            (c2 = [h, context] contiguous)
// [1024,2048)   context      (atomicAdd target, zeroed by k_gru block 0)
// [2048,3072)   v = attn_w^T h
// [3072,7168)   scores

// ---------------- K1: GRU cell -> h (1024 blocks, block per output) ----------------
__global__ __launch_bounds__(256) void k_gru(const int* __restrict__ word,
                                             const float* __restrict__ emb,
                                             const float* __restrict__ h0,
                                             const float* __restrict__ w_ih,
                                             const float* __restrict__ w_hh,
                                             const float* __restrict__ b_ih,
                                             const float* __restrict__ b_hh,
                                             float* __restrict__ ws_h,
                                             float* __restrict__ ws_ctx,
                                             float* __restrict__ out_h)
{
    const int k = blockIdx.x;   // output element 0..1023
    const int t = threadIdx.x;  // 0..255, each owns one float4 (4 columns)

    if (k == 0) {               // zero the context atomic target for this call
#pragma unroll
        for (int i = 0; i < 4; ++i) ws_ctx[t + i * 256] = 0.f;
    }

    const float* x = emb + (size_t)word[0] * Hn;
    const float4 xv = ((const float4*)x)[t];
    const float4 hv = ((const float4*)h0)[t];

    float acc[6];
    const float* rows[6] = {
        w_ih + (size_t)k * Hn, w_ih + (size_t)(k + Hn) * Hn, w_ih + (size_t)(k + 2 * Hn) * Hn,
        w_hh + (size_t)k * Hn, w_hh + (size_t)(k + Hn) * Hn, w_hh + (size_t)(k + 2 * Hn) * Hn
    };
#pragma unroll
    for (int g = 0; g < 6; ++g) {
        const float4 w = ((const float4*)rows[g])[t];
        const float4 vv = (g < 3) ? xv : hv;
        acc[g] = w.x * vv.x + w.y * vv.y + w.z * vv.z + w.w * vv.w;
    }

    __shared__ float red[6][4];
    const int wv = t >> 6, lane = t & 63;
#pragma unroll
    for (int g = 0; g < 6; ++g) {
        const float s = wave_reduce_sum(acc[g]);
        if (lane == 0) red[g][wv] = s;
    }
    __syncthreads();
    if (t == 0) {
        float g0 = red[0][0] + red[0][1] + red[0][2] + red[0][3] + b_ih[k];
        float g1 = red[1][0] + red[1][1] + red[1][2] + red[1][3] + b_ih[k + Hn];
        float g2 = red[2][0] + red[2][1] + red[2][2] + red[2][3] + b_ih[k + 2 * Hn];
        float g3 = red[3][0] + red[3][1] + red[3][2] + red[3][3] + b_hh[k];
        float g4 = red[4][0] + red[4][1] + red[4][2] + red[4][3] + b_hh[k + Hn];
        float g5 = red[5][0] + red[5][1] + red[5][2] + red[5][3] + b_hh[k + 2 * Hn];
        float r = 1.f / (1.f + expf(-(g0 + g3)));
        float z = 1.f / (1.f + expf(-(g1 + g4)));
        float n = tanhf(g2 + r * g5);
        float hk = (1.f - z) * n + z * h0[k];
        ws_h[k]  = hk;
        out_h[k] = hk;
    }
}

// ---------------- K2: v = attn_w^T h (64 blocks, 16-col strip) ----------------
__global__ __launch_bounds__(256) void k_attnv(const float* __restrict__ attn_w,
                                               const float* __restrict__ ws_h,
                                               float* __restrict__ v)
{
    const int t = threadIdx.x;
    const int tj = t >> 4;                 // 0..15 row-group
    const int tk = t & 15;                 // 0..15 column within block
    const int k = blockIdx.x * 16 + tk;
    float acc = 0.f;
    for (int j = tj; j < Hn; j += 16)
        acc += attn_w[(size_t)j * Hn + k] * ws_h[j];
    __shared__ float p[16][17];
    p[tj][tk] = acc;
    __syncthreads();
    if (t < 16) {
        float s = 0.f;
#pragma unroll
        for (int j = 0; j < 16; ++j) s += p[j][t];
        v[blockIdx.x * 16 + t] = s;
    }
}

// ---------------- K3: scores[s] = enc[s] . v ----------------
__global__ __launch_bounds__(256) void k_scores(const float* __restrict__ enc,
                                                const float* __restrict__ ws_v,
                                                float* __restrict__ scores)
{
    __shared__ float v[Hn];
    const int t = threadIdx.x;
    ((float4*)v)[t] = ((const float4*)ws_v)[t];
    __syncthreads();
    const int wv = t >> 6, lane = t & 63;
    const int s = blockIdx.x * 4 + wv;
    const float* row = enc + (size_t)s * Hn;
    float acc = 0.f;
#pragma unroll
    for (int k = 0; k < 4; ++k) {
        const int idx = k * 256 + lane * 4;
        const float4 e = *(const float4*)(row + idx);
        acc += e.x * v[idx] + e.y * v[idx + 1] + e.z * v[idx + 2] + e.w * v[idx + 3];
    }
    acc = wave_reduce_sum(acc);
    if (lane == 0) scores[s] = acc;
}

// -------- K4: softmax (per-block recompute) + context via atomicAdd --------
__global__ __launch_bounds__(256) void k_ctx(const float* __restrict__ enc,
                                             const float* __restrict__ scores,
                                             float* __restrict__ ctx,
                                             float* __restrict__ out_attn)
{
    const int t = threadIdx.x, bid = blockIdx.x;
    const int wv = t >> 6, lane = t & 63;
    __shared__ float red[4];
    __shared__ float aw[64];

    // softmax stats over all 4096 scores (redundant per block; scores are cache-hot)
    float4 sc[4];
#pragma unroll
    for (int i = 0; i < 4; ++i) sc[i] = ((const float4*)scores)[i * 256 + t];
    float m = -1e30f;
#pragma unroll
    for (int i = 0; i < 4; ++i)
        m = fmaxf(m, fmaxf(fmaxf(sc[i].x, sc[i].y), fmaxf(sc[i].z, sc[i].w)));
    m = wave_reduce_max(m);
    if (lane == 0) red[wv] = m;
    __syncthreads();
    const float mx = fmaxf(fmaxf(red[0], red[1]), fmaxf(red[2], red[3]));
    float ps = 0.f;
#pragma unroll
    for (int i = 0; i < 4; ++i)
        ps += expf(sc[i].x - mx) + expf(sc[i].y - mx) + expf(sc[i].z - mx) + expf(sc[i].w - mx);
    ps = wave_reduce_sum(ps);
    __syncthreads();
    if (lane == 0) red[wv] = ps;
    __syncthreads();
    const float inv = 1.f / (red[0] + red[1] + red[2] + red[3]);

    // this block's 64-row chunk of the weighted sum
    const int s0 = bid * 64;
    if (t < 64) {
        const float a = expf(scores[s0 + t] - mx) * inv;
        aw[t] = a;
        out_attn[s0 + t] = a;
    }
    __syncthreads();

    float acc0 = 0.f, acc1 = 0.f, acc2 = 0.f, acc3 = 0.f;
    const float* base = enc + (size_t)s0 * Hn;
#pragma unroll 4
    for (int s = 0; s < 64; ++s) {
        const float a = aw[s];
        const float* row = base + (size_t)s * Hn;
        acc0 += a * row[t];
        acc1 += a * row[t + 256];
        acc2 += a * row[t + 512];
        acc3 += a * row[t + 768];
    }
    atomicAdd(&ctx[t],       acc0);
    atomicAdd(&ctx[t + 256], acc1);
    atomicAdd(&ctx[t + 512], acc2);
    atomicAdd(&ctx[t + 768], acc3);
}

// ---------------- K5: output = out_w . [h, ctx] + out_b ----------------
__global__ __launch_bounds__(256) void k_out(const float* __restrict__ out_w,
                                             const float* __restrict__ out_b,
                                             const float* __restrict__ c2,
                                             float* __restrict__ out)
{
    __shared__ float c[2 * Hn];
    const int t = threadIdx.x;
    ((float4*)c)[t]       = ((const float4*)c2)[t];
    ((float4*)c)[t + 256] = ((const float4*)c2)[t + 256];
    __syncthreads();
    const int wv = t >> 6, lane = t & 63;
    const int row = blockIdx.x * 4 + wv;
    const float* w = out_w + (size_t)row * (2 * Hn);
    float acc = 0.f;
#pragma unroll
    for (int k = 0; k < 8; ++k) {
        const int idx = k * 256 + lane * 4;
        const float4 w4 = *(const float4*)(w + idx);
        acc += w4.x * c[idx] + w4.y * c[idx + 1] + w4.z * c[idx + 2] + w4.w * c[idx + 3];
    }
    acc = wave_reduce_sum(acc);
    if (lane == 0) out[row] = acc + out_b[row];
}

extern "C" void kernel_launch(void* const* d_in, const int* in_sizes, int n_in,
                              void* d_out, int out_size, void* d_ws, size_t ws_size,
                              hipStream_t stream) {
    const int*   word   = (const int*)d_in[0];
    const float* h_last = (const float*)d_in[1];
    const float* enc    = (const float*)d_in[2];
    const float* emb    = (const float*)d_in[3];
    const float* w_ih   = (const float*)d_in[4];
    const float* w_hh   = (const float*)d_in[5];
    const float* b_ih   = (const float*)d_in[6];
    const float* b_hh   = (const float*)d_in[7];
    const float* attn_w = (const float*)d_in[8];
    /* d_in[9] attn_b: unused — uniform shift, softmax-invariant */
    const float* out_w  = (const float*)d_in[10];
    const float* out_b  = (const float*)d_in[11];
    float* out = (float*)d_out;
    float* ws  = (float*)d_ws;

    float* ws_h      = ws;          // 1024
    float* ws_ctx    = ws + 1024;   // 1024 (c2 = [h, ctx] contiguous at ws)
    float* ws_v      = ws + 2048;   // 1024
    float* ws_scores = ws + 3072;   // 4096

    k_gru<<<Hn, 256, 0, stream>>>(word, emb, h_last, w_ih, w_hh, b_ih, b_hh, ws_h, ws_ctx, out + Vn);
    k_attnv<<<Hn / 16, 256, 0, stream>>>(attn_w, ws_h, ws_v);
    k_scores<<<Sn / 4, 256, 0, stream>>>(enc, ws_v, ws_scores);
    k_ctx<<<Sn / 64, 256, 0, stream>>>(enc, ws_scores, ws_ctx, out + Vn + Hn);
    k_out<<<Vn / 4, 256, 0, stream>>>(out_w, out_b, ws, out);
}

// Round 5
// 83.977 us; speedup vs baseline: 2.3621x; 1.0264x over previous
//
#include <hip/hip_runtime.h>
#include <cstddef>

#define Hn 1024
#define Vn 32000
#define Sn 4096

__device__ __forceinline__ float wave_reduce_sum(float v) {
#pragma unroll
    for (int o = 32; o > 0; o >>= 1) v += __shfl_down(v, o, 64);
    return v;
}
__device__ __forceinline__ float wave_reduce_max(float v) {
#pragma unroll
    for (int o = 32; o > 0; o >>= 1) v = fmaxf(v, __shfl_down(v, o, 64));
    return v;
}

// ws layout (floats):
// [0,1024)      h            (c2 = [h, context] contiguous)
// [1024,2048)   context      (atomicAdd target, zeroed by k_gru block 0)
// [2048,3072)   v = attn_w^T h
// [3072,7168)   scores

// out-head h-half: out[row] = out_w[row,0:1024].h + out_b[row]  (4 rows/block)
__device__ __forceinline__ void out_h_rows(const float* __restrict__ out_w,
                                           const float* __restrict__ out_b,
                                           const float* __restrict__ ws_h,
                                           float* __restrict__ out,
                                           int row_base, int t)
{
    __shared__ float c[Hn];
    ((float4*)c)[t] = ((const float4*)ws_h)[t];
    __syncthreads();
    const int wv = t >> 6, lane = t & 63;
    const int row = row_base + wv;
    const float* w = out_w + (size_t)row * (2 * Hn);
    float acc = 0.f;
#pragma unroll
    for (int k = 0; k < 4; ++k) {
        const int idx = k * 256 + lane * 4;
        const float4 w4 = *(const float4*)(w + idx);
        acc += w4.x * c[idx] + w4.y * c[idx + 1] + w4.z * c[idx + 2] + w4.w * c[idx + 3];
    }
    acc = wave_reduce_sum(acc);
    if (lane == 0) out[row] = acc + out_b[row];
}

// ---------------- K1: GRU cell -> h (1024 blocks, block per output) ----------------
__global__ __launch_bounds__(256) void k_gru(const int* __restrict__ word,
                                             const float* __restrict__ emb,
                                             const float* __restrict__ h0,
                                             const float* __restrict__ w_ih,
                                             const float* __restrict__ w_hh,
                                             const float* __restrict__ b_ih,
                                             const float* __restrict__ b_hh,
                                             float* __restrict__ ws_h,
                                             float* __restrict__ ws_ctx,
                                             float* __restrict__ out_h)
{
    const int k = blockIdx.x;
    const int t = threadIdx.x;

    if (k == 0) {               // zero the context atomic target for this call
#pragma unroll
        for (int i = 0; i < 4; ++i) ws_ctx[t + i * 256] = 0.f;
    }

    const float* x = emb + (size_t)word[0] * Hn;
    const float4 xv = ((const float4*)x)[t];
    const float4 hv = ((const float4*)h0)[t];

    float acc[6];
    const float* rows[6] = {
        w_ih + (size_t)k * Hn, w_ih + (size_t)(k + Hn) * Hn, w_ih + (size_t)(k + 2 * Hn) * Hn,
        w_hh + (size_t)k * Hn, w_hh + (size_t)(k + Hn) * Hn, w_hh + (size_t)(k + 2 * Hn) * Hn
    };
#pragma unroll
    for (int g = 0; g < 6; ++g) {
        const float4 w = ((const float4*)rows[g])[t];
        const float4 vv = (g < 3) ? xv : hv;
        acc[g] = w.x * vv.x + w.y * vv.y + w.z * vv.z + w.w * vv.w;
    }

    __shared__ float red[6][4];
    const int wv = t >> 6, lane = t & 63;
#pragma unroll
    for (int g = 0; g < 6; ++g) {
        const float s = wave_reduce_sum(acc[g]);
        if (lane == 0) red[g][wv] = s;
    }
    __syncthreads();
    if (t == 0) {
        float g0 = red[0][0] + red[0][1] + red[0][2] + red[0][3] + b_ih[k];
        float g1 = red[1][0] + red[1][1] + red[1][2] + red[1][3] + b_ih[k + Hn];
        float g2 = red[2][0] + red[2][1] + red[2][2] + red[2][3] + b_ih[k + 2 * Hn];
        float g3 = red[3][0] + red[3][1] + red[3][2] + red[3][3] + b_hh[k];
        float g4 = red[4][0] + red[4][1] + red[4][2] + red[4][3] + b_hh[k + Hn];
        float g5 = red[5][0] + red[5][1] + red[5][2] + red[5][3] + b_hh[k + 2 * Hn];
        float r = 1.f / (1.f + expf(-(g0 + g3)));
        float z = 1.f / (1.f + expf(-(g1 + g4)));
        float n = tanhf(g2 + r * g5);
        float hk = (1.f - z) * n + z * h0[k];
        ws_h[k]  = hk;
        out_h[k] = hk;
    }
}

// ---------------- K2: attnv (blocks 0..63) ∥ out_h rows [0,10668) ----------------
__global__ __launch_bounds__(256) void k_a(const float* __restrict__ attn_w,
                                           const float* __restrict__ ws_h,
                                           float* __restrict__ v,
                                           const float* __restrict__ out_w,
                                           const float* __restrict__ out_b,
                                           float* __restrict__ out)
{
    const int t = threadIdx.x, bid = blockIdx.x;
    if (bid < 64) {
        const int tj = t >> 4, tk = t & 15;
        const int k = bid * 16 + tk;
        float acc = 0.f;
        for (int j = tj; j < Hn; j += 16)
            acc += attn_w[(size_t)j * Hn + k] * ws_h[j];
        __shared__ float p[16][17];
        p[tj][tk] = acc;
        __syncthreads();
        if (t < 16) {
            float s = 0.f;
#pragma unroll
            for (int j = 0; j < 16; ++j) s += p[j][t];
            v[bid * 16 + t] = s;
        }
    } else {
        out_h_rows(out_w, out_b, ws_h, out, (bid - 64) * 4, t);
    }
}

// ---------------- K3: scores (blocks 0..1023) ∥ out_h rows [10668,21336) ----------------
__global__ __launch_bounds__(256) void k_b(const float* __restrict__ enc,
                                           const float* __restrict__ ws_v,
                                           float* __restrict__ scores,
                                           const float* __restrict__ ws_h,
                                           const float* __restrict__ out_w,
                                           const float* __restrict__ out_b,
                                           float* __restrict__ out)
{
    const int t = threadIdx.x, bid = blockIdx.x;
    if (bid < 1024) {
        __shared__ float vsm[Hn];
        ((float4*)vsm)[t] = ((const float4*)ws_v)[t];
        __syncthreads();
        const int wv = t >> 6, lane = t & 63;
        const int s = bid * 4 + wv;
        const float* row = enc + (size_t)s * Hn;
        float acc = 0.f;
#pragma unroll
        for (int k = 0; k < 4; ++k) {
            const int idx = k * 256 + lane * 4;
            const float4 e = *(const float4*)(row + idx);
            acc += e.x * vsm[idx] + e.y * vsm[idx + 1] + e.z * vsm[idx + 2] + e.w * vsm[idx + 3];
        }
        acc = wave_reduce_sum(acc);
        if (lane == 0) scores[s] = acc;
    } else {
        out_h_rows(out_w, out_b, ws_h, out, 10668 + (bid - 1024) * 4, t);
    }
}

// ------- K4: ctx+softmax (blocks 0..63) ∥ out_h rows [21336,32000) -------
__global__ __launch_bounds__(256) void k_c(const float* __restrict__ enc,
                                           const float* __restrict__ scores,
                                           float* __restrict__ ctx,
                                           float* __restrict__ out_attn,
                                           const float* __restrict__ ws_h,
                                           const float* __restrict__ out_w,
                                           const float* __restrict__ out_b,
                                           float* __restrict__ out)
{
    const int t = threadIdx.x, bid = blockIdx.x;
    if (bid < 64) {
        const int wv = t >> 6, lane = t & 63;
        __shared__ float red[4];
        __shared__ float aw[64];

        float4 sc[4];
#pragma unroll
        for (int i = 0; i < 4; ++i) sc[i] = ((const float4*)scores)[i * 256 + t];
        float m = -1e30f;
#pragma unroll
        for (int i = 0; i < 4; ++i)
            m = fmaxf(m, fmaxf(fmaxf(sc[i].x, sc[i].y), fmaxf(sc[i].z, sc[i].w)));
        m = wave_reduce_max(m);
        if (lane == 0) red[wv] = m;
        __syncthreads();
        const float mx = fmaxf(fmaxf(red[0], red[1]), fmaxf(red[2], red[3]));
        float ps = 0.f;
#pragma unroll
        for (int i = 0; i < 4; ++i)
            ps += expf(sc[i].x - mx) + expf(sc[i].y - mx) + expf(sc[i].z - mx) + expf(sc[i].w - mx);
        ps = wave_reduce_sum(ps);
        __syncthreads();
        if (lane == 0) red[wv] = ps;
        __syncthreads();
        const float inv = 1.f / (red[0] + red[1] + red[2] + red[3]);

        const int s0 = bid * 64;
        if (t < 64) {
            const float a = expf(scores[s0 + t] - mx) * inv;
            aw[t] = a;
            out_attn[s0 + t] = a;
        }
        __syncthreads();

        float acc0 = 0.f, acc1 = 0.f, acc2 = 0.f, acc3 = 0.f;
        const float* base = enc + (size_t)s0 * Hn;
#pragma unroll 4
        for (int s = 0; s < 64; ++s) {
            const float a = aw[s];
            const float* row = base + (size_t)s * Hn;
            acc0 += a * row[t];
            acc1 += a * row[t + 256];
            acc2 += a * row[t + 512];
            acc3 += a * row[t + 768];
        }
        atomicAdd(&ctx[t],       acc0);
        atomicAdd(&ctx[t + 256], acc1);
        atomicAdd(&ctx[t + 512], acc2);
        atomicAdd(&ctx[t + 768], acc3);
    } else {
        out_h_rows(out_w, out_b, ws_h, out, 21336 + (bid - 64) * 4, t);
    }
}

// ---------------- K5: out[row] += out_w[row,1024:2048] . ctx ----------------
__global__ __launch_bounds__(256) void k_out_ctx(const float* __restrict__ out_w,
                                                 const float* __restrict__ ws_ctx,
                                                 float* __restrict__ out)
{
    __shared__ float c[Hn];
    const int t = threadIdx.x;
    ((float4*)c)[t] = ((const float4*)ws_ctx)[t];
    __syncthreads();
    const int wv = t >> 6, lane = t & 63;
    const int row = blockIdx.x * 4 + wv;
    const float* w = out_w + (size_t)row * (2 * Hn) + Hn;
    float acc = 0.f;
#pragma unroll
    for (int k = 0; k < 4; ++k) {
        const int idx = k * 256 + lane * 4;
        const float4 w4 = *(const float4*)(w + idx);
        acc += w4.x * c[idx] + w4.y * c[idx + 1] + w4.z * c[idx + 2] + w4.w * c[idx + 3];
    }
    acc = wave_reduce_sum(acc);
    if (lane == 0) out[row] += acc;
}

extern "C" void kernel_launch(void* const* d_in, const int* in_sizes, int n_in,
                              void* d_out, int out_size, void* d_ws, size_t ws_size,
                              hipStream_t stream) {
    const int*   word   = (const int*)d_in[0];
    const float* h_last = (const float*)d_in[1];
    const float* enc    = (const float*)d_in[2];
    const float* emb    = (const float*)d_in[3];
    const float* w_ih   = (const float*)d_in[4];
    const float* w_hh   = (const float*)d_in[5];
    const float* b_ih   = (const float*)d_in[6];
    const float* b_hh   = (const float*)d_in[7];
    const float* attn_w = (const float*)d_in[8];
    /* d_in[9] attn_b: unused — uniform shift, softmax-invariant */
    const float* out_w  = (const float*)d_in[10];
    const float* out_b  = (const float*)d_in[11];
    float* out = (float*)d_out;
    float* ws  = (float*)d_ws;

    float* ws_h      = ws;          // 1024
    float* ws_ctx    = ws + 1024;   // 1024 (c2 = [h, ctx] contiguous at ws)
    float* ws_v      = ws + 2048;   // 1024
    float* ws_scores = ws + 3072;   // 4096

    k_gru<<<Hn, 256, 0, stream>>>(word, emb, h_last, w_ih, w_hh, b_ih, b_hh, ws_h, ws_ctx, out + Vn);
    k_a<<<64 + 2667, 256, 0, stream>>>(attn_w, ws_h, ws_v, out_w, out_b, out);
    k_b<<<1024 + 2667, 256, 0, stream>>>(enc, ws_v, ws_scores, ws_h, out_w, out_b, out);
    k_c<<<64 + 2666, 256, 0, stream>>>(enc, ws_scores, ws_ctx, out + Vn + Hn, ws_h, out_w, out_b, out);
    k_out_ctx<<<Vn / 4, 256, 0, stream>>>(out_w, ws_ctx, out);
}